// Round 17
// baseline (116.773 us; speedup 1.0000x reference)
//
#include <hip/hip_runtime.h>
#include <math.h>

#define D_BINS 59
#define CO     64
#define CI     256
#define NB     4
#define NC     6
#define H_IMG  16
#define W_IMG  44
#define HW     704            // H_IMG * W_IMG
#define NPIX   (NB*NC*HW)     // 16896
#define XD     128
#define YD     128
#define ZD     7
#define NZ     (NC*ZD)        // 42 samples per (x,y,b)
#define NOUT   123            // D_BINS + CO
#define PXT    64             // pixels per k_head tile: 16896 = 264*64; 704 = 11*64
#define NTILE  264

typedef float v2f  __attribute__((ext_vector_type(2)));
typedef short short8 __attribute__((ext_vector_type(8)));
typedef float f32x4  __attribute__((ext_vector_type(4)));

// round-to-nearest-even fp32 -> bf16 (bit pattern), and back
__device__ inline unsigned short f2bf(float f) {
    unsigned u = __float_as_uint(f);
    return (unsigned short)((u + 0x7FFFu + ((u >> 16) & 1u)) >> 16);
}
__device__ inline float bf2f(unsigned short h) {
    return __uint_as_float((unsigned)h << 16);
}

// ---------------------------------------------------------------------------
// Double-precision rigid-transform inverse (matches np.linalg.inv to ~1e-15).
// ---------------------------------------------------------------------------
__device__ void inv_rigid(const float* __restrict__ M, float* __restrict__ o) {
    double a = M[0], b = M[1], c = M[2], t0 = M[3];
    double d = M[4], e = M[5], f = M[6], t1 = M[7];
    double g = M[8], h = M[9], ii = M[10], t2 = M[11];
    double A00 = e*ii - f*h, A01 = c*h - b*ii, A02 = b*f - c*e;
    double A10 = f*g - d*ii, A11 = a*ii - c*g, A12 = c*d - a*f;
    double A20 = d*h - e*g,  A21 = b*g - a*h,  A22 = a*e - b*d;
    double det = a*A00 + b*A10 + c*A20;
    double inv = 1.0 / det;
    double r00 = A00*inv, r01 = A01*inv, r02 = A02*inv;
    double r10 = A10*inv, r11 = A11*inv, r12 = A12*inv;
    double r20 = A20*inv, r21 = A21*inv, r22 = A22*inv;
    o[0] = (float)r00; o[1] = (float)r01; o[2]  = (float)r02;
    o[3] = (float)(-(r00*t0 + r01*t1 + r02*t2));
    o[4] = (float)r10; o[5] = (float)r11; o[6]  = (float)r12;
    o[7] = (float)(-(r10*t0 + r11*t1 + r12*t2));
    o[8] = (float)r20; o[9] = (float)r21; o[10] = (float)r22;
    o[11] = (float)(-(r20*t0 + r21*t1 + r22*t2));
}

// ---------------------------------------------------------------------------
// Kernel 1: prep. W (123x256) -> split-bf16 pair whi/wlo, row-major [o][k],
// o zero-padded to 128. Block 0 also inverts cam2ego. Unchanged from R12.
// ---------------------------------------------------------------------------
__global__ __launch_bounds__(256) void k_pre(
    const float* __restrict__ wd, const float* __restrict__ c2e,
    unsigned short* __restrict__ whi, unsigned short* __restrict__ wlo,
    float* __restrict__ e2c) {
    const int o = blockIdx.x;   // 0..127
    const int k = threadIdx.x;  // 0..255
    float f = (o < NOUT) ? wd[(size_t)o * CI + k] : 0.f;
    unsigned short hi = f2bf(f);
    whi[o * 256 + k] = hi;
    wlo[o * 256 + k] = f2bf(f - bf2f(hi));
    if (blockIdx.x == 0 && k < NB * NC)
        inv_rigid(c2e + k * 16, e2c + k * 12);
}

// ---------------------------------------------------------------------------
// Kernel 2: MFMA depth/feat head (split-bf16). R15 version, byte-identical
// (the 114.5 us best): lane=px coalesced staging, conflict-free swizzled
// short8 b128 LDS writes, 96 mfma_f32_16x16x32_bf16/wave, R0-form epilogue.
// ---------------------------------------------------------------------------
__global__ __launch_bounds__(512) void k_head(
    const float* __restrict__ img, const unsigned short* __restrict__ whi_g,
    const unsigned short* __restrict__ wlo_g, const float* __restrict__ bd,
    float* __restrict__ depth_out, float* __restrict__ feat_ws) {
    __shared__ __align__(16) unsigned short Bbuf[2 * PXT * 256]; // 64 KB
    __shared__ float S[PXT];
    unsigned short* BH = Bbuf;
    unsigned short* BL = Bbuf + PXT * 256;

    const int tid = threadIdx.x;
    const int wv  = tid >> 6;            // 0..7 -> o-tile / staging c-group
    const int ln  = tid & 63;
    const int lm  = ln & 15;             // fragment row/col lane index
    const int lg  = ln >> 4;             // k-group
    const int p0  = blockIdx.x * PXT;

    const int bn  = p0 / HW;             // tile within one (b,n): 704 = 11*64
    const int hw0 = p0 - bn * HW;        // 64-aligned
    const float* gsrc = img + (size_t)bn * CI * HW + hw0;

    // ---- stage A tile: lane = px; wave w -> channels [32w, 32w+32) ----
    {
        const int c0 = wv * 32;
        float rvv[32];
#pragma unroll
        for (int j = 0; j < 32; ++j)     // 32 coalesced 256B dword rows
            rvv[j] = gsrc[(size_t)(c0 + j) * HW + ln];
#pragma unroll
        for (int r = 0; r < 4; ++r) {
            const int kk = c0 + r * 8;
            short8 hi8, lo8;
#pragma unroll
            for (int j = 0; j < 8; ++j) {
                float f = rvv[r * 8 + j];
                unsigned short hi = f2bf(f);
                hi8[j] = (short)hi;
                lo8[j] = (short)f2bf(f - bf2f(hi));
            }
            const int si = (ln * 256 + kk) ^ ((ln & 7) << 3);
            *(short8*)(BH + si) = hi8;   // b128, 8 lanes/bank-group: free
            *(short8*)(BL + si) = lo8;
        }
    }
    __syncthreads();

    // ---- MFMA main loop: no barriers ----
    f32x4 acc[4];
#pragma unroll
    for (int t = 0; t < 4; ++t) acc[t] = (f32x4)(0.f);

    const unsigned short* wh = whi_g + (size_t)(wv * 16 + lm) * 256;
    const unsigned short* wl = wlo_g + (size_t)(wv * 16 + lm) * 256;

#pragma unroll
    for (int s = 0; s < 8; ++s) {
        const int kk = s * 32 + lg * 8;
        short8 a_hi = *(const short8*)(wh + kk);   // 16B, L2-hot, 4x reuse
        short8 a_lo = *(const short8*)(wl + kk);
#pragma unroll
        for (int t = 0; t < 4; ++t) {
            int px = t * 16 + lm;
            int si = (px * 256 + kk) ^ ((px & 7) << 3);
            short8 b_hi = *(const short8*)(BH + si);
            short8 b_lo = *(const short8*)(BL + si);
            acc[t] = __builtin_amdgcn_mfma_f32_16x16x32_bf16(a_hi, b_hi, acc[t], 0, 0, 0);
            acc[t] = __builtin_amdgcn_mfma_f32_16x16x32_bf16(a_hi, b_lo, acc[t], 0, 0, 0);
            acc[t] = __builtin_amdgcn_mfma_f32_16x16x32_bf16(a_lo, b_hi, acc[t], 0, 0, 0);
        }
    }
    __syncthreads();          // all B reads done -> X may alias Bbuf

    // ---- epilogue into X[64][132]: logits col o (<59), feat col o+5 ----
    float* X = (float*)Bbuf;  // 64*132*4 = 33.8 KB < 64 KB
    const int ob = wv * 16 + lg * 4;     // o base for this lane's regs
#pragma unroll
    for (int t = 0; t < 4; ++t) {
        int px = t * 16 + lm;
#pragma unroll
        for (int r = 0; r < 4; ++r) {
            int o = ob + r;
            if (o < NOUT) {
                int col = (o < D_BINS) ? o : o + 5;
                X[px * 132 + col] = acc[t][r] + bd[o];
            }
        }
    }
    __syncthreads();

    // feat: X[p][64..127] -> feat_ws, coalesced float4 (1024 of them)
    for (int g = tid; g < PXT * 16; g += 512) {
        int p = g >> 4, m = g & 15;
        float4 v = *(const float4*)(X + p * 132 + 64 + m * 4);
        *(float4*)(feat_ws + (size_t)(p0 + p) * CO + m * 4) = v;
    }

    // softmax over cols 0..58, one thread per pixel (R0 form)
    if (tid < PXT) {
        float* row = X + tid * 132;
        float m = row[0];
        for (int o = 1; o < D_BINS; ++o) m = fmaxf(m, row[o]);
        float s = 0.f;
        for (int o = 0; o < D_BINS; ++o) {
            float e = __expf(row[o] - m);
            row[o] = e;
            s += e;
        }
        S[tid] = 1.f / s;
    }
    __syncthreads();

    // depth: tile region contiguous [p0*59, (p0+64)*59) -> coalesced
    for (int g = tid; g < PXT * D_BINS; g += 512) {
        int p = g / D_BINS;
        int o = g - p * D_BINS;
        depth_out[(size_t)p0 * D_BINS + g] = X[p * 132 + o] * S[p];
    }
}

// ---------------------------------------------------------------------------
// Kernel 3: project voxels, gather depth weight + feat, splat to BEV.
// NEW this round: SINGLE projection phase + BARRIER-FREE accumulate.
// R16's occupancy fix (+16 waves/CU) bought only 1.3 us -> the cost is the
// serial phase structure: 6 cameras x {project, barrier, accumulate,
// barrier} = 12 barriers, each fencing the gather pipeline every 7 samples.
// All 42 (n,z) projections are independent: compute them in ONE phase
// (thread (tx,ty) owns s = ty+8i, all depth_g gathers in flight together),
// one barrier, then accumulate across all 42 samples with ZERO barriers --
// compiler can pipeline the 42 feat gathers across the whole loop.
// FMA chain keeps exact (n-outer, z-ascending) order with identical
// operands -> BIT-IDENTICAL output. Barriers/block: 13 -> 2.
// LDS 21.5 KB; 8-channel split + __launch_bounds__(512,8) kept from R16.
// ---------------------------------------------------------------------------
__global__ __launch_bounds__(512, 8) void k_splat(
    const float* __restrict__ e2c, const float* __restrict__ Kmat,
    const float* __restrict__ depth_g, const float* __restrict__ feat_ws,
    float* __restrict__ bev) {
    __shared__ int   hw_s[NZ][64];
    __shared__ float wgt_s[NZ][64];

    const int tx = threadIdx.x;          // 0..63 -> x
    const int ty = threadIdx.y;          // 0..7  -> channel octet / sample group
    const int x = blockIdx.x * 64 + tx;
    const int y = blockIdx.y;
    const int b = blockIdx.z;
    const float wx = (float)x * 0.8f + (-51.2f);
    const float wy = (float)y * 0.8f + (-51.2f);

    // ---- projection phase: ALL 42 (n,z) samples, one pass ----
    for (int i = 0; i < 6; ++i) {
        const int s = ty + 8 * i;
        if (s < NZ) {
            const int n = s / ZD;
            const int z = s - n * ZD;
            const int bn = b * NC + n;
            const float* E = e2c + bn * 12;
            const float* Km = Kmat + bn * 9;
            const float k00 = Km[0], k01 = Km[1], k02 = Km[2];
            const float k10 = Km[3], k11 = Km[4], k12 = Km[5];
            const float e02 = E[2], e12 = E[6], e22 = E[10];
            const float bx0 = E[0] * wx + E[1] * wy + E[3];
            const float bx1 = E[4] * wx + E[5] * wy + E[7];
            const float bx2 = E[8] * wx + E[9] * wy + E[11];
            const float wz = -2.5f + (float)z;
            const float cx = bx0 + e02 * wz;
            const float cy = bx1 + e12 * wz;
            const float cz = bx2 + e22 * wz;
            const float zs = fmaxf(cz, 0.1f);
            const float rz = 1.0f / zs;         // IEEE divide
            const float xn = cx * rz;
            const float yn = cy * rz;
            const float fu = (k00 * xn + k01 * yn + k02) * 0.0625f;
            const float fv = (k10 * xn + k11 * yn + k12) * 0.0625f;
            const int bin = (int)(cz - 1.0f);   // trunc, matches astype(int32)
            const bool valid = (fu >= 0.f) & (fu < (float)W_IMG) &
                               (fv >= 0.f) & (fv < (float)H_IMG) &
                               (cz > 0.5f) & (bin >= 0) & (bin < D_BINS);
            int hw = -1;
            float wgt = 0.f;
            if (valid) {
                int u = (int)fu;                // valid => in range
                int v = (int)fv;
                hw = v * W_IMG + u;
                wgt = depth_g[((size_t)bn * HW + hw) * D_BINS + bin];
            }
            hw_s[s][tx] = hw;
            wgt_s[s][tx] = wgt;
        }
    }
    __syncthreads();

    // ---- accumulate: all 42 samples, ZERO barriers, exact (n,z) order ----
    float acc[8];
#pragma unroll
    for (int m = 0; m < 8; ++m) acc[m] = 0.f;

    for (int n = 0; n < NC; ++n) {
        const int bn = b * NC + n;
        const float* fbase = feat_ws + (size_t)bn * HW * CO + ty * 8;
#pragma unroll
        for (int z = 0; z < ZD; ++z) {
            const int hw = hw_s[n * ZD + z][tx];   // 8 ty threads: broadcast
            if (hw >= 0) {
                const float wgt = wgt_s[n * ZD + z][tx];
                const float4* fp = (const float4*)(fbase + (size_t)hw * CO);
                float4 f0 = fp[0], f1 = fp[1];
                acc[0] = fmaf(wgt, f0.x, acc[0]);
                acc[1] = fmaf(wgt, f0.y, acc[1]);
                acc[2] = fmaf(wgt, f0.z, acc[2]);
                acc[3] = fmaf(wgt, f0.w, acc[3]);
                acc[4] = fmaf(wgt, f1.x, acc[4]);
                acc[5] = fmaf(wgt, f1.y, acc[5]);
                acc[6] = fmaf(wgt, f1.z, acc[6]);
                acc[7] = fmaf(wgt, f1.w, acc[7]);
            }
        }
    }
    // out[b][c][y][x], c = ty*8 + m; 64 lanes = consecutive x -> coalesced
    float* ob = bev + (((size_t)b * CO + ty * 8) * YD + y) * XD + x;
#pragma unroll
    for (int m = 0; m < 8; ++m) ob[(size_t)m * YD * XD] = acc[m];
}

extern "C" void kernel_launch(void* const* d_in, const int* in_sizes, int n_in,
                              void* d_out, int out_size, void* d_ws, size_t ws_size,
                              hipStream_t stream) {
    const float* img  = (const float*)d_in[0];  // (B,N,256,16,44)
    const float* c2e  = (const float*)d_in[1];  // (B,N,4,4)
    const float* Kmat = (const float*)d_in[2];  // (B,N,3,3)
    const float* wd   = (const float*)d_in[3];  // (123,256)
    const float* bd   = (const float*)d_in[4];  // (123,)
    float* bev = (float*)d_out;                         // (B,64,128,128)
    float* depth_out = bev + (size_t)NB * CO * YD * XD; // (B,N,16,44,59)
    float* feat_ws = (float*)d_ws;                      // NPIX*64 floats
    unsigned short* whi = (unsigned short*)(feat_ws + (size_t)NPIX * CO); // 64KB
    unsigned short* wlo = whi + 128 * 256;                                // 64KB
    float* e2c = (float*)(wlo + 128 * 256);             // 24*12 floats

    k_pre<<<128, 256, 0, stream>>>(wd, c2e, whi, wlo, e2c);
    k_head<<<NTILE, 512, 0, stream>>>(img, whi, wlo, bd, depth_out, feat_ws);
    k_splat<<<dim3(2, YD, NB), dim3(64, 8, 1), 0, stream>>>(e2c, Kmat, depth_out,
                                                            feat_ws, bev);
}

// Round 18
// 114.353 us; speedup vs baseline: 1.0212x; 1.0212x over previous
//
#include <hip/hip_runtime.h>
#include <math.h>

#define D_BINS 59
#define CO     64
#define CI     256
#define NB     4
#define NC     6
#define H_IMG  16
#define W_IMG  44
#define HW     704            // H_IMG * W_IMG
#define NPIX   (NB*NC*HW)     // 16896
#define XD     128
#define YD     128
#define ZD     7
#define NOUT   123            // D_BINS + CO
#define PXT    64             // pixels per k_head tile: 16896 = 264*64; 704 = 11*64
#define NTILE  264

typedef float v2f  __attribute__((ext_vector_type(2)));
typedef short short8 __attribute__((ext_vector_type(8)));
typedef float f32x4  __attribute__((ext_vector_type(4)));

// round-to-nearest-even fp32 -> bf16 (bit pattern), and back
__device__ inline unsigned short f2bf(float f) {
    unsigned u = __float_as_uint(f);
    return (unsigned short)((u + 0x7FFFu + ((u >> 16) & 1u)) >> 16);
}
__device__ inline float bf2f(unsigned short h) {
    return __uint_as_float((unsigned)h << 16);
}

// ---------------------------------------------------------------------------
// Double-precision rigid-transform inverse (matches np.linalg.inv to ~1e-15).
// ---------------------------------------------------------------------------
__device__ void inv_rigid(const float* __restrict__ M, float* __restrict__ o) {
    double a = M[0], b = M[1], c = M[2], t0 = M[3];
    double d = M[4], e = M[5], f = M[6], t1 = M[7];
    double g = M[8], h = M[9], ii = M[10], t2 = M[11];
    double A00 = e*ii - f*h, A01 = c*h - b*ii, A02 = b*f - c*e;
    double A10 = f*g - d*ii, A11 = a*ii - c*g, A12 = c*d - a*f;
    double A20 = d*h - e*g,  A21 = b*g - a*h,  A22 = a*e - b*d;
    double det = a*A00 + b*A10 + c*A20;
    double inv = 1.0 / det;
    double r00 = A00*inv, r01 = A01*inv, r02 = A02*inv;
    double r10 = A10*inv, r11 = A11*inv, r12 = A12*inv;
    double r20 = A20*inv, r21 = A21*inv, r22 = A22*inv;
    o[0] = (float)r00; o[1] = (float)r01; o[2]  = (float)r02;
    o[3] = (float)(-(r00*t0 + r01*t1 + r02*t2));
    o[4] = (float)r10; o[5] = (float)r11; o[6]  = (float)r12;
    o[7] = (float)(-(r10*t0 + r11*t1 + r12*t2));
    o[8] = (float)r20; o[9] = (float)r21; o[10] = (float)r22;
    o[11] = (float)(-(r20*t0 + r21*t1 + r22*t2));
}

// ---------------------------------------------------------------------------
// Kernel 1: prep. W (123x256) -> split-bf16 pair whi/wlo, row-major [o][k],
// o zero-padded to 128. Block 0 also inverts cam2ego. Unchanged from R12.
// ---------------------------------------------------------------------------
__global__ __launch_bounds__(256) void k_pre(
    const float* __restrict__ wd, const float* __restrict__ c2e,
    unsigned short* __restrict__ whi, unsigned short* __restrict__ wlo,
    float* __restrict__ e2c) {
    const int o = blockIdx.x;   // 0..127
    const int k = threadIdx.x;  // 0..255
    float f = (o < NOUT) ? wd[(size_t)o * CI + k] : 0.f;
    unsigned short hi = f2bf(f);
    whi[o * 256 + k] = hi;
    wlo[o * 256 + k] = f2bf(f - bf2f(hi));
    if (blockIdx.x == 0 && k < NB * NC)
        inv_rigid(c2e + k * 16, e2c + k * 12);
}

// ---------------------------------------------------------------------------
// Kernel 2: MFMA depth/feat head (split-bf16). R15/R16 version, byte-
// identical (the 114.5 us best): lane=px coalesced staging, conflict-free
// swizzled short8 b128 LDS writes, 96 mfma_f32_16x16x32_bf16/wave,
// R0-form epilogue.
// ---------------------------------------------------------------------------
__global__ __launch_bounds__(512) void k_head(
    const float* __restrict__ img, const unsigned short* __restrict__ whi_g,
    const unsigned short* __restrict__ wlo_g, const float* __restrict__ bd,
    float* __restrict__ depth_out, float* __restrict__ feat_ws) {
    __shared__ __align__(16) unsigned short Bbuf[2 * PXT * 256]; // 64 KB
    __shared__ float S[PXT];
    unsigned short* BH = Bbuf;
    unsigned short* BL = Bbuf + PXT * 256;

    const int tid = threadIdx.x;
    const int wv  = tid >> 6;            // 0..7 -> o-tile / staging c-group
    const int ln  = tid & 63;
    const int lm  = ln & 15;             // fragment row/col lane index
    const int lg  = ln >> 4;             // k-group
    const int p0  = blockIdx.x * PXT;

    const int bn  = p0 / HW;             // tile within one (b,n): 704 = 11*64
    const int hw0 = p0 - bn * HW;        // 64-aligned
    const float* gsrc = img + (size_t)bn * CI * HW + hw0;

    // ---- stage A tile: lane = px; wave w -> channels [32w, 32w+32) ----
    {
        const int c0 = wv * 32;
        float rvv[32];
#pragma unroll
        for (int j = 0; j < 32; ++j)     // 32 coalesced 256B dword rows
            rvv[j] = gsrc[(size_t)(c0 + j) * HW + ln];
#pragma unroll
        for (int r = 0; r < 4; ++r) {
            const int kk = c0 + r * 8;
            short8 hi8, lo8;
#pragma unroll
            for (int j = 0; j < 8; ++j) {
                float f = rvv[r * 8 + j];
                unsigned short hi = f2bf(f);
                hi8[j] = (short)hi;
                lo8[j] = (short)f2bf(f - bf2f(hi));
            }
            const int si = (ln * 256 + kk) ^ ((ln & 7) << 3);
            *(short8*)(BH + si) = hi8;   // b128, 8 lanes/bank-group: free
            *(short8*)(BL + si) = lo8;
        }
    }
    __syncthreads();

    // ---- MFMA main loop: no barriers ----
    f32x4 acc[4];
#pragma unroll
    for (int t = 0; t < 4; ++t) acc[t] = (f32x4)(0.f);

    const unsigned short* wh = whi_g + (size_t)(wv * 16 + lm) * 256;
    const unsigned short* wl = wlo_g + (size_t)(wv * 16 + lm) * 256;

#pragma unroll
    for (int s = 0; s < 8; ++s) {
        const int kk = s * 32 + lg * 8;
        short8 a_hi = *(const short8*)(wh + kk);   // 16B, L2-hot, 4x reuse
        short8 a_lo = *(const short8*)(wl + kk);
#pragma unroll
        for (int t = 0; t < 4; ++t) {
            int px = t * 16 + lm;
            int si = (px * 256 + kk) ^ ((px & 7) << 3);
            short8 b_hi = *(const short8*)(BH + si);
            short8 b_lo = *(const short8*)(BL + si);
            acc[t] = __builtin_amdgcn_mfma_f32_16x16x32_bf16(a_hi, b_hi, acc[t], 0, 0, 0);
            acc[t] = __builtin_amdgcn_mfma_f32_16x16x32_bf16(a_hi, b_lo, acc[t], 0, 0, 0);
            acc[t] = __builtin_amdgcn_mfma_f32_16x16x32_bf16(a_lo, b_hi, acc[t], 0, 0, 0);
        }
    }
    __syncthreads();          // all B reads done -> X may alias Bbuf

    // ---- epilogue into X[64][132]: logits col o (<59), feat col o+5 ----
    float* X = (float*)Bbuf;  // 64*132*4 = 33.8 KB < 64 KB
    const int ob = wv * 16 + lg * 4;     // o base for this lane's regs
#pragma unroll
    for (int t = 0; t < 4; ++t) {
        int px = t * 16 + lm;
#pragma unroll
        for (int r = 0; r < 4; ++r) {
            int o = ob + r;
            if (o < NOUT) {
                int col = (o < D_BINS) ? o : o + 5;
                X[px * 132 + col] = acc[t][r] + bd[o];
            }
        }
    }
    __syncthreads();

    // feat: X[p][64..127] -> feat_ws, coalesced float4 (1024 of them)
    for (int g = tid; g < PXT * 16; g += 512) {
        int p = g >> 4, m = g & 15;
        float4 v = *(const float4*)(X + p * 132 + 64 + m * 4);
        *(float4*)(feat_ws + (size_t)(p0 + p) * CO + m * 4) = v;
    }

    // softmax over cols 0..58, one thread per pixel (R0 form)
    if (tid < PXT) {
        float* row = X + tid * 132;
        float m = row[0];
        for (int o = 1; o < D_BINS; ++o) m = fmaxf(m, row[o]);
        float s = 0.f;
        for (int o = 0; o < D_BINS; ++o) {
            float e = __expf(row[o] - m);
            row[o] = e;
            s += e;
        }
        S[tid] = 1.f / s;
    }
    __syncthreads();

    // depth: tile region contiguous [p0*59, (p0+64)*59) -> coalesced
    for (int g = tid; g < PXT * D_BINS; g += 512) {
        int p = g / D_BINS;
        int o = g - p * D_BINS;
        depth_out[(size_t)p0 * D_BINS + g] = X[p * 132 + o] * S[p];
    }
}

// ---------------------------------------------------------------------------
// Kernel 3: project voxels, gather depth weight + feat, splat to BEV.
// R16 version, byte-identical (the 114.5 us best): 8-way channel split,
// __launch_bounds__(512,8) under the 64-VGPR cliff -> 32 waves/CU; per-
// camera {project(z=ty), barrier, accumulate z-ascending, barrier} phases.
// (R17's single-phase/barrier-free variant regressed 2.3 us -> reverted.)
// ---------------------------------------------------------------------------
__global__ __launch_bounds__(512, 8) void k_splat(
    const float* __restrict__ e2c, const float* __restrict__ Kmat,
    const float* __restrict__ depth_g, const float* __restrict__ feat_ws,
    float* __restrict__ bev) {
    __shared__ int   hw_s[ZD][64];
    __shared__ float wgt_s[ZD][64];

    const int tx = threadIdx.x;          // 0..63 -> x
    const int ty = threadIdx.y;          // 0..7  -> channel octet / z-slice
    const int x = blockIdx.x * 64 + tx;
    const int y = blockIdx.y;
    const int b = blockIdx.z;
    const float wx = (float)x * 0.8f + (-51.2f);
    const float wy = (float)y * 0.8f + (-51.2f);

    float acc[8];
#pragma unroll
    for (int m = 0; m < 8; ++m) acc[m] = 0.f;

    for (int n = 0; n < NC; ++n) {
        const int bn = b * NC + n;

        // ---- projection phase: thread (tx,ty) owns z = ty (ty<7) ----
        if (ty < ZD) {
            const float* E = e2c + bn * 12;
            const float* Km = Kmat + bn * 9;
            const float k00 = Km[0], k01 = Km[1], k02 = Km[2];
            const float k10 = Km[3], k11 = Km[4], k12 = Km[5];
            const float e02 = E[2], e12 = E[6], e22 = E[10];
            const float bx0 = E[0] * wx + E[1] * wy + E[3];
            const float bx1 = E[4] * wx + E[5] * wy + E[7];
            const float bx2 = E[8] * wx + E[9] * wy + E[11];
            const int z = ty;
            const float wz = -2.5f + (float)z;
            const float cx = bx0 + e02 * wz;
            const float cy = bx1 + e12 * wz;
            const float cz = bx2 + e22 * wz;
            const float zs = fmaxf(cz, 0.1f);
            const float rz = 1.0f / zs;         // IEEE divide
            const float xn = cx * rz;
            const float yn = cy * rz;
            const float fu = (k00 * xn + k01 * yn + k02) * 0.0625f;
            const float fv = (k10 * xn + k11 * yn + k12) * 0.0625f;
            const int bin = (int)(cz - 1.0f);   // trunc, matches astype(int32)
            const bool valid = (fu >= 0.f) & (fu < (float)W_IMG) &
                               (fv >= 0.f) & (fv < (float)H_IMG) &
                               (cz > 0.5f) & (bin >= 0) & (bin < D_BINS);
            int hw = -1;
            float wgt = 0.f;
            if (valid) {
                int u = (int)fu;                // valid => in range
                int v = (int)fv;
                hw = v * W_IMG + u;
                wgt = depth_g[((size_t)bn * HW + hw) * D_BINS + bin];
            }
            hw_s[z][tx] = hw;
            wgt_s[z][tx] = wgt;
        }
        __syncthreads();

        // ---- accumulate phase: z ascending (same order as baseline) ----
#pragma unroll
        for (int z = 0; z < ZD; ++z) {
            const int hw = hw_s[z][tx];       // 8 ty threads same addr: broadcast
            if (hw >= 0) {
                const float wgt = wgt_s[z][tx];
                const float4* fp =
                    (const float4*)(feat_ws + ((size_t)bn * HW + hw) * CO + ty * 8);
                float4 f0 = fp[0], f1 = fp[1];
                acc[0] = fmaf(wgt, f0.x, acc[0]);
                acc[1] = fmaf(wgt, f0.y, acc[1]);
                acc[2] = fmaf(wgt, f0.z, acc[2]);
                acc[3] = fmaf(wgt, f0.w, acc[3]);
                acc[4] = fmaf(wgt, f1.x, acc[4]);
                acc[5] = fmaf(wgt, f1.y, acc[5]);
                acc[6] = fmaf(wgt, f1.z, acc[6]);
                acc[7] = fmaf(wgt, f1.w, acc[7]);
            }
        }
        __syncthreads();   // LDS reused next n
    }
    // out[b][c][y][x], c = ty*8 + m; 64 lanes = consecutive x -> coalesced
    float* ob = bev + (((size_t)b * CO + ty * 8) * YD + y) * XD + x;
#pragma unroll
    for (int m = 0; m < 8; ++m) ob[(size_t)m * YD * XD] = acc[m];
}

extern "C" void kernel_launch(void* const* d_in, const int* in_sizes, int n_in,
                              void* d_out, int out_size, void* d_ws, size_t ws_size,
                              hipStream_t stream) {
    const float* img  = (const float*)d_in[0];  // (B,N,256,16,44)
    const float* c2e  = (const float*)d_in[1];  // (B,N,4,4)
    const float* Kmat = (const float*)d_in[2];  // (B,N,3,3)
    const float* wd   = (const float*)d_in[3];  // (123,256)
    const float* bd   = (const float*)d_in[4];  // (123,)
    float* bev = (float*)d_out;                         // (B,64,128,128)
    float* depth_out = bev + (size_t)NB * CO * YD * XD; // (B,N,16,44,59)
    float* feat_ws = (float*)d_ws;                      // NPIX*64 floats
    unsigned short* whi = (unsigned short*)(feat_ws + (size_t)NPIX * CO); // 64KB
    unsigned short* wlo = whi + 128 * 256;                                // 64KB
    float* e2c = (float*)(wlo + 128 * 256);             // 24*12 floats

    k_pre<<<128, 256, 0, stream>>>(wd, c2e, whi, wlo, e2c);
    k_head<<<NTILE, 512, 0, stream>>>(img, whi, wlo, bd, depth_out, feat_ws);
    k_splat<<<dim3(2, YD, NB), dim3(64, 8, 1), 0, stream>>>(e2c, Kmat, depth_out,
                                                            feat_ws, bev);
}